// Round 5
// baseline (150.124 us; speedup 1.0000x reference)
//
#include <hip/hip_runtime.h>

// Problem constants (match reference)
constexpr int N    = 8192;     // nodes
constexpr int NE   = 131072;   // edges
constexpr int WPR  = N / 32;   // 256 u32 words per bitset row
constexpr int MAXD = 64;       // max distinct out-degree (Poisson(16); P(>64) ~ 1e-19)

// f(k) = exp(-ALPHA*k), ALPHA = 2
#define F1 0.13533528323661270f   // e^-2
#define F2 0.018315638888734179f  // e^-4
#define F3 0.0024787521766663585f // e^-6

// ---------------------------------------------------------------------------
// Fused MLP: angles = relu(relu(relu(X@W0)@W1)@W2) @ W3.
// One block = 32 rows, 256 threads, thread = 2 rows x 8 cols.
// LDS-pressure-optimized: x values preloaded 8-at-a-time per row via
// ds_read_b128 (Xs stride 132 spreads the 16 rp addresses over 4 bank
// quads); W pair-swizzled at word 12*cg (2-way bank aliasing = free).
// ---------------------------------------------------------------------------
__global__ __launch_bounds__(256) void mlp_kernel(
    const float* __restrict__ X,
    const float* __restrict__ W0, const float* __restrict__ W1,
    const float* __restrict__ W2, const float* __restrict__ W3,
    float* __restrict__ angles)
{
    __shared__ float Xs[32 * 132];   // padded stride 132 (528 B, 16B-aligned)
    __shared__ float Ws[64 * 192];   // swizzled half of W

    const int tid  = threadIdx.x;
    const int row0 = blockIdx.x * 32;
    const int cg   = tid & 15;       // col-group (8 cols)
    const int rp   = tid >> 4;       // row-pair id, 0..15
    const int r0   = rp * 2;
    const int c0   = cg * 8;

    // stage coeffs tile (32 rows x 128) into padded layout
    for (int q = tid; q < 32 * 32; q += 256) {
        float4 v = *(const float4*)&X[row0 * 128 + q * 4];
        *(float4*)&Xs[(q >> 5) * 132 + (q & 31) * 4] = v;
    }

    float acc[2][8];
    for (int layer = 0; layer < 3; ++layer) {
        const float* __restrict__ W = (layer == 0) ? W0 : (layer == 1) ? W1 : W2;

#pragma unroll
        for (int r = 0; r < 2; ++r)
#pragma unroll
            for (int c = 0; c < 8; ++c) acc[r][c] = 0.0f;

        for (int kh = 0; kh < 2; ++kh) {
            __syncthreads();   // prev compute / Xs writes done before restage
            // stage 64 rows of W, swizzled: chunk j of row k -> word
            // k*192 + (j>>1)*12 + (j&1)*4
#pragma unroll
            for (int it = 0; it < 8; ++it) {
                int q = tid + it * 256;        // 0..2047 float4 chunks
                int k = q >> 5;                // row within half
                int j = q & 31;                // float4 chunk within row
                float4 v = *(const float4*)&W[(kh * 64 + k) * 128 + j * 4];
                *(float4*)&Ws[k * 192 + (j >> 1) * 12 + (j & 1) * 4] = v;
            }
            __syncthreads();

            for (int k8 = 0; k8 < 8; ++k8) {
                // preload x: 2 rows x 8 k in 4 b128 reads
                const float* xp0 = &Xs[r0 * 132 + kh * 64 + k8 * 8];
                const float* xp1 = &Xs[(r0 + 1) * 132 + kh * 64 + k8 * 8];
                float4 xa0 = *(const float4*)xp0;
                float4 xb0 = *(const float4*)(xp0 + 4);
                float4 xa1 = *(const float4*)xp1;
                float4 xb1 = *(const float4*)(xp1 + 4);
                float x0a[8] = {xa0.x, xa0.y, xa0.z, xa0.w, xb0.x, xb0.y, xb0.z, xb0.w};
                float x1a[8] = {xa1.x, xa1.y, xa1.z, xa1.w, xb1.x, xb1.y, xb1.z, xb1.w};
#pragma unroll
                for (int j = 0; j < 8; ++j) {
                    const int kk = k8 * 8 + j;
                    const float4 wa = *(const float4*)&Ws[kk * 192 + cg * 12];
                    const float4 wb = *(const float4*)&Ws[kk * 192 + cg * 12 + 4];
                    const float x0 = x0a[j];
                    const float x1 = x1a[j];
                    acc[0][0] += x0 * wa.x; acc[0][1] += x0 * wa.y;
                    acc[0][2] += x0 * wa.z; acc[0][3] += x0 * wa.w;
                    acc[0][4] += x0 * wb.x; acc[0][5] += x0 * wb.y;
                    acc[0][6] += x0 * wb.z; acc[0][7] += x0 * wb.w;
                    acc[1][0] += x1 * wa.x; acc[1][1] += x1 * wa.y;
                    acc[1][2] += x1 * wa.z; acc[1][3] += x1 * wa.w;
                    acc[1][4] += x1 * wb.x; acc[1][5] += x1 * wb.y;
                    acc[1][6] += x1 * wb.z; acc[1][7] += x1 * wb.w;
                }
            }
        }

#pragma unroll
        for (int r = 0; r < 2; ++r)
#pragma unroll
            for (int c = 0; c < 8; ++c) acc[r][c] = fmaxf(acc[r][c], 0.0f);

        __syncthreads();   // everyone done reading Xs before overwrite

        if (layer < 2) {
            // write h back into Xs (next layer's X), padded layout
#pragma unroll
            for (int r = 0; r < 2; ++r) {
                *(float4*)&Xs[(r0 + r) * 132 + c0] =
                    make_float4(acc[r][0], acc[r][1], acc[r][2], acc[r][3]);
                *(float4*)&Xs[(r0 + r) * 132 + c0 + 4] =
                    make_float4(acc[r][4], acc[r][5], acc[r][6], acc[r][7]);
            }
        } else {
            // final dot with W3 (L2-hot broadcast)
            const float4 w3a = *(const float4*)&W3[c0];
            const float4 w3b = *(const float4*)&W3[c0 + 4];
            float p0 = acc[0][0] * w3a.x + acc[0][1] * w3a.y + acc[0][2] * w3a.z +
                       acc[0][3] * w3a.w + acc[0][4] * w3b.x + acc[0][5] * w3b.y +
                       acc[0][6] * w3b.z + acc[0][7] * w3b.w;
            float p1 = acc[1][0] * w3a.x + acc[1][1] * w3a.y + acc[1][2] * w3a.z +
                       acc[1][3] * w3a.w + acc[1][4] * w3b.x + acc[1][5] * w3b.y +
                       acc[1][6] * w3b.z + acc[1][7] * w3b.w;
#pragma unroll
            for (int m = 1; m < 16; m <<= 1) {
                p0 += __shfl_xor(p0, m, 64);
                p1 += __shfl_xor(p1, m, 64);
            }
            if (cg == 0) {
                angles[row0 + r0]     = p0;
                angles[row0 + r0 + 1] = p1;
            }
        }
    }
}

// ---------------------------------------------------------------------------
// Merged edge pass: bitset adjacency (dedup by OR) + inline CSR build
// (atomicOr returns old word -> exactly-once insertion per distinct (r,c))
// + hop-1 scatter over the RAW edge list (duplicates counted, per reference).
// ---------------------------------------------------------------------------
__global__ void edges_kernel(const int* __restrict__ ei,
                             const float* __restrict__ angles,
                             unsigned int* __restrict__ adj,
                             float* __restrict__ s1,
                             int* __restrict__ cnt_g,
                             int* __restrict__ nbr_g)
{
    int e = blockIdx.x * blockDim.x + threadIdx.x;
    if (e < NE) {
        int r = ei[e];
        int c = ei[NE + e];
        unsigned int bit = 1u << (c & 31);
        unsigned int old = atomicOr(&adj[r * WPR + (c >> 5)], bit);
        if (!(old & bit)) {
            int p = atomicAdd(&cnt_g[r], 1);
            if (p < MAXD) nbr_g[r * MAXD + p] = c;
        }
        atomicAdd(&s1[r], F1 * angles[c]);
    }
}

// ---------------------------------------------------------------------------
// P2 row i = 2-hop union via CSR: for each nbr m of i, set bits of m's nbr
// list in a per-wave LDS bitmap (1 KB). Reads ~16x64 B instead of ~16x1 KB.
// One wave per row, 4 rows/block. Writes P2 bitmap (stride-64 lane layout,
// same as before) + sparse dot vs e1 (= angles+s1, never materialized).
// Epilogue: s2/e2.
// ---------------------------------------------------------------------------
__global__ __launch_bounds__(256) void p2_kernel(
    const int* __restrict__ cnt_g, const int* __restrict__ nbr_g,
    unsigned int* __restrict__ P2,
    const float* __restrict__ angles, const float* __restrict__ s1,
    float* __restrict__ s2, float* __restrict__ e2)
{
    __shared__ unsigned int bm[4][WPR];  // 4 KB: per-wave bitmap
    __shared__ int nbr[4][MAXD];
    __shared__ int nc[4][MAXD];

    const int wv = threadIdx.x >> 6;
    const int l  = threadIdx.x & 63;
    const int i  = blockIdx.x * 4 + wv;

#pragma unroll
    for (int s = 0; s < 4; ++s) bm[wv][s * 64 + l] = 0u;

    const int n = min(cnt_g[i], MAXD);
    if (l < n) {
        int m = nbr_g[i * MAXD + l];
        nbr[wv][l] = m;
        nc[wv][l]  = min(cnt_g[m], MAXD);
    }
    __syncthreads();

    for (int q = 0; q < n; ++q) {
        int m  = nbr[wv][q];   // wave-uniform LDS broadcast
        int c2 = nc[wv][q];
        if (l < c2) {
            int id = nbr_g[m * MAXD + l];   // 64B coalesced
            atomicOr(&bm[wv][id >> 5], 1u << (id & 31));
        }
    }
    __syncthreads();

    unsigned int w[4];
#pragma unroll
    for (int s = 0; s < 4; ++s) {
        w[s] = bm[wv][s * 64 + l];
        P2[(size_t)i * WPR + s * 64 + l] = w[s];
    }

    // sparse dot: ~4 set bits/lane -> ffs iterate, gather e1 on the fly
    float local = 0.0f;
#pragma unroll
    for (int s = 0; s < 4; ++s) {
        unsigned int ww = w[s];
        const int base = (s * 64 + l) * 32;
        while (ww) {
            int b = __ffs(ww) - 1;
            ww &= ww - 1;
            local += angles[base + b] + s1[base + b];
        }
    }
#pragma unroll
    for (int m = 1; m < 64; m <<= 1) local += __shfl_xor(local, m, 64);
    if (l == 0) {
        float e1i = angles[i] + s1[i];
        float s2v = s1[i] + F2 * local;
        s2[i] = s2v;
        e2[i] = e1i + s2v;
    }
}

// ---------------------------------------------------------------------------
// P3 row i (never materialized) = OR of P2 rows of i's neighbors.
// out[i] = e2[i] + s2[i] + F3 * (P3[i] . e2)
// One wave per row. Dense dot: 32 chunks; lane l reads float4 e2[c*256+4l]
// (coalesced 1KB/instr); mask nibble fetched from the owning lane with one
// __shfl per chunk (register slot c>>3 is uniform).
// ---------------------------------------------------------------------------
__global__ __launch_bounds__(256) void p3_kernel(
    const unsigned int* __restrict__ P2,
    const int* __restrict__ cnt_g, const int* __restrict__ nbr_g,
    const float* __restrict__ e2, const float* __restrict__ s2,
    float* __restrict__ out)
{
    __shared__ int nbr[4][MAXD];

    const int wv = threadIdx.x >> 6;
    const int l  = threadIdx.x & 63;
    const int i  = blockIdx.x * 4 + wv;

    const int n = min(cnt_g[i], MAXD);
    if (l < n) nbr[wv][l] = nbr_g[i * MAXD + l];
    __syncthreads();

    unsigned int w[4] = {0u, 0u, 0u, 0u};
    for (int q = 0; q < n; ++q) {
        const unsigned int* rowp = P2 + (size_t)nbr[wv][q] * WPR + l;
#pragma unroll
        for (int s = 0; s < 4; ++s) w[s] |= rowp[s * 64];
    }

    float local = 0.0f;
#pragma unroll
    for (int c = 0; c < 32; ++c) {
        unsigned int wd  = __shfl(w[c >> 3], ((c & 7) << 3) | (l >> 3), 64);
        unsigned int nib = wd >> ((l & 7) * 4);
        float4 v = *(const float4*)&e2[c * 256 + l * 4];
        local += (nib & 1u) ? v.x : 0.0f;
        local += (nib & 2u) ? v.y : 0.0f;
        local += (nib & 4u) ? v.z : 0.0f;
        local += (nib & 8u) ? v.w : 0.0f;
    }
#pragma unroll
    for (int m = 1; m < 64; m <<= 1) local += __shfl_xor(local, m, 64);
    if (l == 0)
        out[i] = e2[i] + s2[i] + F3 * local;
}

// ---------------------------------------------------------------------------
// Launch
// ---------------------------------------------------------------------------
extern "C" void kernel_launch(void* const* d_in, const int* in_sizes, int n_in,
                              void* d_out, int out_size, void* d_ws, size_t ws_size,
                              hipStream_t stream)
{
    const float* coeffs = (const float*)d_in[0];
    const float* W0     = (const float*)d_in[1];
    const float* W1     = (const float*)d_in[2];
    const float* W2     = (const float*)d_in[3];
    const float* W3     = (const float*)d_in[4];
    const int*   ei     = (const int*)  d_in[5];
    float* out = (float*)d_out;

    char* ws = (char*)d_ws;
    // workspace layout (bytes)
    float*        angles = (float*)(ws + 0 * 32768);
    float*        s2     = (float*)(ws + 1 * 32768);
    float*        e2     = (float*)(ws + 2 * 32768);
    int*          nbr_g  = (int*)  (ws + 3 * 32768);           // 2 MB
    unsigned int* adj    = (unsigned int*)(ws + (4u  << 20));  // 8 MB
    float*        s1     = (float*)(ws + (12u << 20));         // 32 KB, after adj
    int*          cnt_g  = (int*)  (ws + (12u << 20) + 32768); // 32 KB, after s1
    unsigned int* P2     = (unsigned int*)(ws + (13u << 20));  // 8 MB

    // one memset covers adj (8 MB) + s1 + cnt_g (contiguous)
    hipMemsetAsync(adj, 0,
                   ((size_t)N * WPR) * sizeof(unsigned int) + 2 * N * sizeof(float),
                   stream);

    // MLP: single fused kernel
    mlp_kernel<<<N / 32, 256, 0, stream>>>(coeffs, W0, W1, W2, W3, angles);

    // graph side
    edges_kernel<<<NE / 256, 256, 0, stream>>>(ei, angles, adj, s1, cnt_g, nbr_g);
    p2_kernel<<<N / 4, 256, 0, stream>>>(cnt_g, nbr_g, P2, angles, s1, s2, e2);
    p3_kernel<<<N / 4, 256, 0, stream>>>(P2, cnt_g, nbr_g, e2, s2, out);
}